// Round 5
// baseline (971.609 us; speedup 1.0000x reference)
//
#include <hip/hip_runtime.h>

// ---------------------------------------------------------------------------
// HabitatGNN: 2-layer GCN (with self loops, symmetric norm) + linear head.
// x:[N,128] f32, edge_index:[2,E] int32 (harness converts integer inputs to
// int32!), W1:[128,64], W2:[64,32], Wc:[32,1], out:[N,1] f32.
//
// Pipeline:
//   deg (int atomics) -> dinv = rsqrt(deg+1)
//   h1 = x @ W1                      (dense, LDS-staged W)
//   agg1 += norm(e) * h1[src]        (edge scatter, fp32 atomics)
//   hr1 = relu(agg1 + dinv^2*h1 + b1)   (self-loop folded here)
//   h2 = hr1 @ W2
//   agg2 += norm(e) * h2[src]
//   out = relu(agg2 + dinv^2*h2 + b2) @ Wc + bc   (fused final)
// ---------------------------------------------------------------------------

__global__ __launch_bounds__(256) void count_kernel(const int* __restrict__ dst,
                                                    int* __restrict__ deg, int E) {
    int e = blockIdx.x * blockDim.x + threadIdx.x;
    if (e < E) atomicAdd(&deg[dst[e]], 1);
}

__global__ __launch_bounds__(256) void dinv_kernel(const int* __restrict__ deg,
                                                   float* __restrict__ dinv, int n) {
    int i = blockIdx.x * blockDim.x + threadIdx.x;
    if (i < n) dinv[i] = rsqrtf((float)(deg[i] + 1));  // +1 = self loop
}

// H[n, OUT] = X[n, IN] @ W[IN, OUT]; W staged in LDS, one node per thread.
template <int IN, int OUT>
__global__ __launch_bounds__(256) void gemm_kernel(const float* __restrict__ X,
                                                   const float* __restrict__ W,
                                                   float* __restrict__ H, int n) {
    __shared__ float Ws[IN * OUT];
    for (int i = threadIdx.x; i < IN * OUT / 4; i += blockDim.x)
        ((float4*)Ws)[i] = ((const float4*)W)[i];
    __syncthreads();

    int node = blockIdx.x * blockDim.x + threadIdx.x;
    if (node >= n) return;

    float acc[OUT];
#pragma unroll
    for (int j = 0; j < OUT; ++j) acc[j] = 0.f;

    const float* xr = X + (size_t)node * IN;
#pragma unroll 4
    for (int k = 0; k < IN; k += 4) {
        float4 xv = *(const float4*)(xr + k);
        const float* w0 = Ws + (k + 0) * OUT;
        const float* w1 = Ws + (k + 1) * OUT;
        const float* w2 = Ws + (k + 2) * OUT;
        const float* w3 = Ws + (k + 3) * OUT;
#pragma unroll
        for (int j = 0; j < OUT; j += 4) {
            float4 a = *(const float4*)(w0 + j);
            float4 b = *(const float4*)(w1 + j);
            float4 c = *(const float4*)(w2 + j);
            float4 d = *(const float4*)(w3 + j);
            acc[j + 0] += xv.x * a.x + xv.y * b.x + xv.z * c.x + xv.w * d.x;
            acc[j + 1] += xv.x * a.y + xv.y * b.y + xv.z * c.y + xv.w * d.y;
            acc[j + 2] += xv.x * a.z + xv.y * b.z + xv.z * c.z + xv.w * d.z;
            acc[j + 3] += xv.x * a.w + xv.y * b.w + xv.z * c.w + xv.w * d.w;
        }
    }

    float* hr = H + (size_t)node * OUT;
#pragma unroll
    for (int j = 0; j < OUT; j += 4)
        *(float4*)(hr + j) = make_float4(acc[j], acc[j + 1], acc[j + 2], acc[j + 3]);
}

// One edge handled by F/4 threads, each does a float4 gather + 4 atomic adds.
template <int F>
__global__ __launch_bounds__(256) void scatter_kernel(const int* __restrict__ src,
                                                      const int* __restrict__ dst,
                                                      const float* __restrict__ dinv,
                                                      const float* __restrict__ H,
                                                      float* __restrict__ AGG, int E) {
    constexpr int TPE = F / 4;  // threads per edge (power of 2)
    int t = blockIdx.x * blockDim.x + threadIdx.x;
    int e = t / TPE;
    int c = t % TPE;
    if (e >= E) return;
    int s = src[e];
    int d = dst[e];
    float norm = dinv[s] * dinv[d];
    float4 v = *(const float4*)(H + (size_t)s * F + c * 4);
    float* o = AGG + (size_t)d * F + c * 4;
    atomicAdd(o + 0, norm * v.x);
    atomicAdd(o + 1, norm * v.y);
    atomicAdd(o + 2, norm * v.z);
    atomicAdd(o + 3, norm * v.w);
}

// AGG = relu(AGG + dinv^2 * H + b)   (adds self-loop message + bias, in place)
template <int F>
__global__ __launch_bounds__(256) void finish_relu_kernel(float* __restrict__ AGG,
                                                          const float* __restrict__ H,
                                                          const float* __restrict__ dinv,
                                                          const float* __restrict__ b,
                                                          int n) {
    int idx = blockIdx.x * blockDim.x + threadIdx.x;
    if (idx >= n * F) return;
    int node = idx / F;
    int j = idx % F;
    float di = dinv[node];
    float v = AGG[idx] + di * di * H[idx] + b[j];
    AGG[idx] = v > 0.f ? v : 0.f;
}

// out[i] = relu(agg2[i] + dinv^2*h2[i] + b2) . Wc + bc
__global__ __launch_bounds__(256) void final_kernel(const float* __restrict__ AGG2,
                                                    const float* __restrict__ H2,
                                                    const float* __restrict__ dinv,
                                                    const float* __restrict__ b2,
                                                    const float* __restrict__ Wc,
                                                    const float* __restrict__ bc,
                                                    float* __restrict__ out, int n) {
    int node = blockIdx.x * blockDim.x + threadIdx.x;
    if (node >= n) return;
    float di = dinv[node];
    float d2 = di * di;
    const float* a = AGG2 + (size_t)node * 32;
    const float* h = H2 + (size_t)node * 32;
    float acc = 0.f;
#pragma unroll
    for (int j = 0; j < 32; ++j) {
        float v = a[j] + d2 * h[j] + b2[j];
        v = v > 0.f ? v : 0.f;
        acc += v * Wc[j];
    }
    out[node] = acc + bc[0];
}

extern "C" void kernel_launch(void* const* d_in, const int* in_sizes, int n_in,
                              void* d_out, int out_size, void* d_ws, size_t ws_size,
                              hipStream_t stream) {
    const float* x  = (const float*)d_in[0];
    const int*   ei = (const int*)d_in[1];  // integer inputs arrive as int32
    const float* W1 = (const float*)d_in[2];
    const float* b1 = (const float*)d_in[3];
    const float* W2 = (const float*)d_in[4];
    const float* b2 = (const float*)d_in[5];
    const float* Wc = (const float*)d_in[6];
    const float* bc = (const float*)d_in[7];
    float* out = (float*)d_out;

    const int n = in_sizes[0] / 128;   // 100000 nodes
    const int E = in_sizes[1] / 2;     // 600000 edges (in_sizes[1] = 1.2M int32)

    const int* src = ei;               // row 0: [0, E)
    const int* dst = ei + (size_t)E;   // row 1: [E, 2E)

    // Workspace layout (floats): dinv[n] | deg[n] | bufA[n*64] | bufB[n*64]
    float* dinv = (float*)d_ws;
    int*   deg  = (int*)d_ws + n;
    float* bufA = (float*)d_ws + 2 * (size_t)n;          // h1; later h2 + agg2
    float* bufB = bufA + (size_t)n * 64;                 // agg1 -> hr1

    hipMemsetAsync(deg, 0, (size_t)n * 4, stream);
    hipMemsetAsync(bufB, 0, (size_t)n * 64 * 4, stream);

    count_kernel<<<(E + 255) / 256, 256, 0, stream>>>(dst, deg, E);
    dinv_kernel<<<(n + 255) / 256, 256, 0, stream>>>(deg, dinv, n);

    // Layer 1
    gemm_kernel<128, 64><<<(n + 255) / 256, 256, 0, stream>>>(x, W1, bufA, n);
    {
        int threads = E * 16;
        scatter_kernel<64><<<(threads + 255) / 256, 256, 0, stream>>>(src, dst, dinv,
                                                                      bufA, bufB, E);
    }
    finish_relu_kernel<64><<<(n * 64 + 255) / 256, 256, 0, stream>>>(bufB, bufA, dinv, b1, n);

    // Layer 2 (h2 and agg2 alias the dead h1 region)
    float* h2   = bufA;
    float* agg2 = bufA + (size_t)n * 32;
    hipMemsetAsync(agg2, 0, (size_t)n * 32 * 4, stream);

    gemm_kernel<64, 32><<<(n + 255) / 256, 256, 0, stream>>>(bufB, W2, h2, n);
    {
        int threads = E * 8;
        scatter_kernel<32><<<(threads + 255) / 256, 256, 0, stream>>>(src, dst, dinv,
                                                                      h2, agg2, E);
    }
    final_kernel<<<(n + 255) / 256, 256, 0, stream>>>(agg2, h2, dinv, b2, Wc, bc, out, n);
}

// Round 6
// 553.857 us; speedup vs baseline: 1.7543x; 1.7543x over previous
//
#include <hip/hip_runtime.h>

// ---------------------------------------------------------------------------
// HabitatGNN: 2-layer GCN (self loops, symmetric norm) + linear head.
// x:[N,128] f32, edge_index:[2,E] int32 (harness converts ints to int32),
// W1:[128,64], W2:[64,32], Wc:[32,1], out:[N,1] f32.
//
// R5 counters: atomic scatter was 75% of runtime (WRITE_SIZE 614MB = 38.4M
// x 16B atomic transactions; VALUBusy 1.4%). This version builds a CSR
// (counting sort by dst) and aggregates by GATHER: zero f32 atomics.
//
//   deg (int atomics) -> scan (1 block): row_ptr, cursor, dinv
//   fill: col[pos++] = src  (E int atomics)
//   h1 = x @ W1
//   hr1[i] = relu(dinv[i]*Sum_e dinv[col]*h1[col] + dinv[i]^2*h1[i] + b1)
//   h2 = hr1 @ W2
//   out[i] = relu(same agg of h2) . Wc + bc     (fused dot + shfl reduce)
// ---------------------------------------------------------------------------

__global__ __launch_bounds__(256) void count_kernel(const int* __restrict__ dst,
                                                    int* __restrict__ deg, int E) {
    int e = blockIdx.x * blockDim.x + threadIdx.x;
    if (e < E) atomicAdd(&deg[dst[e]], 1);
}

// Single-block scan: row_ptr = exclusive prefix of deg; deg becomes the fill
// cursor (same values); dinv = rsqrt(deg+1) computed on the fly.
#define SCAN_T 1024
__global__ __launch_bounds__(SCAN_T) void scan_kernel(int* __restrict__ deg,
                                                      int* __restrict__ row_ptr,
                                                      float* __restrict__ dinv,
                                                      int n) {
    __shared__ int ssum[SCAN_T];
    int chunk = (n + SCAN_T - 1) / SCAN_T;
    int t = threadIdx.x;
    int begin = t * chunk;
    int end = begin + chunk < n ? begin + chunk : n;

    int local = 0;
    for (int i = begin; i < end; ++i) local += deg[i];
    ssum[t] = local;
    __syncthreads();
    // Hillis-Steele inclusive scan over the 1024 partials
    for (int off = 1; off < SCAN_T; off <<= 1) {
        int v = (t >= off) ? ssum[t - off] : 0;
        __syncthreads();
        ssum[t] += v;
        __syncthreads();
    }
    int prefix = (t == 0) ? 0 : ssum[t - 1];
    for (int i = begin; i < end; ++i) {
        int d = deg[i];
        row_ptr[i] = prefix;
        deg[i] = prefix;                       // becomes cursor for fill
        dinv[i] = rsqrtf((float)(d + 1));      // +1 = self loop
        prefix += d;
    }
    if (t == SCAN_T - 1) row_ptr[n] = prefix;  // == E
}

__global__ __launch_bounds__(256) void fill_kernel(const int* __restrict__ src,
                                                   const int* __restrict__ dst,
                                                   int* __restrict__ cursor,
                                                   int* __restrict__ col, int E) {
    int e = blockIdx.x * blockDim.x + threadIdx.x;
    if (e < E) {
        int pos = atomicAdd(&cursor[dst[e]], 1);
        col[pos] = src[e];
    }
}

// H[n, OUT] = X[n, IN] @ W[IN, OUT]; W staged in LDS, one node per thread.
template <int IN, int OUT>
__global__ __launch_bounds__(256) void gemm_kernel(const float* __restrict__ X,
                                                   const float* __restrict__ W,
                                                   float* __restrict__ H, int n) {
    __shared__ float Ws[IN * OUT];
    for (int i = threadIdx.x; i < IN * OUT / 4; i += blockDim.x)
        ((float4*)Ws)[i] = ((const float4*)W)[i];
    __syncthreads();

    int node = blockIdx.x * blockDim.x + threadIdx.x;
    if (node >= n) return;

    float acc[OUT];
#pragma unroll
    for (int j = 0; j < OUT; ++j) acc[j] = 0.f;

    const float* xr = X + (size_t)node * IN;
#pragma unroll 4
    for (int k = 0; k < IN; k += 4) {
        float4 xv = *(const float4*)(xr + k);
        const float* w0 = Ws + (k + 0) * OUT;
        const float* w1 = Ws + (k + 1) * OUT;
        const float* w2 = Ws + (k + 2) * OUT;
        const float* w3 = Ws + (k + 3) * OUT;
#pragma unroll
        for (int j = 0; j < OUT; j += 4) {
            float4 a = *(const float4*)(w0 + j);
            float4 b = *(const float4*)(w1 + j);
            float4 c = *(const float4*)(w2 + j);
            float4 d = *(const float4*)(w3 + j);
            acc[j + 0] += xv.x * a.x + xv.y * b.x + xv.z * c.x + xv.w * d.x;
            acc[j + 1] += xv.x * a.y + xv.y * b.y + xv.z * c.y + xv.w * d.y;
            acc[j + 2] += xv.x * a.z + xv.y * b.z + xv.z * c.z + xv.w * d.z;
            acc[j + 3] += xv.x * a.w + xv.y * b.w + xv.z * c.w + xv.w * d.w;
        }
    }

    float* hr = H + (size_t)node * OUT;
#pragma unroll
    for (int j = 0; j < OUT; j += 4)
        *(float4*)(hr + j) = make_float4(acc[j], acc[j + 1], acc[j + 2], acc[j + 3]);
}

// Gather aggregation, F/4 threads per node, each owns a float4 column.
// OUT[i] = relu(dinv[i]*Sum dinv[s]*H[s] + dinv[i]^2*H[i] + b)
template <int F>
__global__ __launch_bounds__(256) void agg_relu_kernel(const int* __restrict__ row_ptr,
                                                       const int* __restrict__ col,
                                                       const float* __restrict__ dinv,
                                                       const float* __restrict__ H,
                                                       const float* __restrict__ b,
                                                       float* __restrict__ OUT, int n) {
    constexpr int TPE = F / 4;
    int t = blockIdx.x * blockDim.x + threadIdx.x;
    int node = t / TPE;
    int c = t % TPE;
    if (node >= n) return;
    int rs = row_ptr[node], re = row_ptr[node + 1];
    float di = dinv[node];
    float4 acc = make_float4(0.f, 0.f, 0.f, 0.f);
    for (int e = rs; e < re; ++e) {
        int s = col[e];
        float w = dinv[s];
        float4 v = *(const float4*)(H + (size_t)s * F + c * 4);
        acc.x += w * v.x; acc.y += w * v.y; acc.z += w * v.z; acc.w += w * v.w;
    }
    float4 hs = *(const float4*)(H + (size_t)node * F + c * 4);
    float4 bb = *(const float4*)(b + c * 4);
    float d2 = di * di;
    float4 r;
    r.x = di * acc.x + d2 * hs.x + bb.x;
    r.y = di * acc.y + d2 * hs.y + bb.y;
    r.z = di * acc.z + d2 * hs.z + bb.z;
    r.w = di * acc.w + d2 * hs.w + bb.w;
    r.x = r.x > 0.f ? r.x : 0.f;
    r.y = r.y > 0.f ? r.y : 0.f;
    r.z = r.z > 0.f ? r.z : 0.f;
    r.w = r.w > 0.f ? r.w : 0.f;
    *(float4*)(OUT + (size_t)node * F + c * 4) = r;
}

// Layer-2 aggregation fused with the classifier head:
// out[i] = relu(agg(H2)[i] + b2) . Wc + bc  (8 lanes per node, shfl reduce)
__global__ __launch_bounds__(256) void agg_final_kernel(const int* __restrict__ row_ptr,
                                                        const int* __restrict__ col,
                                                        const float* __restrict__ dinv,
                                                        const float* __restrict__ H,
                                                        const float* __restrict__ b2,
                                                        const float* __restrict__ Wc,
                                                        const float* __restrict__ bc,
                                                        float* __restrict__ out, int n) {
    constexpr int F = 32, TPE = 8;
    int t = blockIdx.x * blockDim.x + threadIdx.x;
    int node = t / TPE;
    int c = t % TPE;
    if (node >= n) return;
    int rs = row_ptr[node], re = row_ptr[node + 1];
    float di = dinv[node];
    float4 acc = make_float4(0.f, 0.f, 0.f, 0.f);
    for (int e = rs; e < re; ++e) {
        int s = col[e];
        float w = dinv[s];
        float4 v = *(const float4*)(H + (size_t)s * F + c * 4);
        acc.x += w * v.x; acc.y += w * v.y; acc.z += w * v.z; acc.w += w * v.w;
    }
    float4 hs = *(const float4*)(H + (size_t)node * F + c * 4);
    float4 bb = *(const float4*)(b2 + c * 4);
    float4 wc = *(const float4*)(Wc + c * 4);
    float d2 = di * di;
    float4 r;
    r.x = di * acc.x + d2 * hs.x + bb.x;
    r.y = di * acc.y + d2 * hs.y + bb.y;
    r.z = di * acc.z + d2 * hs.z + bb.z;
    r.w = di * acc.w + d2 * hs.w + bb.w;
    float dot = (r.x > 0.f ? r.x : 0.f) * wc.x + (r.y > 0.f ? r.y : 0.f) * wc.y +
                (r.z > 0.f ? r.z : 0.f) * wc.z + (r.w > 0.f ? r.w : 0.f) * wc.w;
    // reduce across the 8 lanes of this node (contiguous lane group)
    dot += __shfl_xor(dot, 1, 8);
    dot += __shfl_xor(dot, 2, 8);
    dot += __shfl_xor(dot, 4, 8);
    if (c == 0) out[node] = dot + bc[0];
}

extern "C" void kernel_launch(void* const* d_in, const int* in_sizes, int n_in,
                              void* d_out, int out_size, void* d_ws, size_t ws_size,
                              hipStream_t stream) {
    const float* x  = (const float*)d_in[0];
    const int*   ei = (const int*)d_in[1];  // int32 edge_index
    const float* W1 = (const float*)d_in[2];
    const float* b1 = (const float*)d_in[3];
    const float* W2 = (const float*)d_in[4];
    const float* b2 = (const float*)d_in[5];
    const float* Wc = (const float*)d_in[6];
    const float* bc = (const float*)d_in[7];
    float* out = (float*)d_out;

    const int n = in_sizes[0] / 128;   // 100000
    const int E = in_sizes[1] / 2;     // 600000

    const int* src = ei;
    const int* dst = ei + (size_t)E;

    // ws layout (4B elems): dinv[n] | deg/cursor[n] | row_ptr[n+1] | col[E]
    //                       | bufA[64n] | bufB[64n]           (~54.8 MB)
    float* dinv    = (float*)d_ws;
    int*   deg     = (int*)d_ws + n;           // becomes fill cursor after scan
    int*   row_ptr = (int*)d_ws + 2 * (size_t)n;
    int*   col     = row_ptr + (n + 1);
    float* bufA    = (float*)(col + E);        // h1, then h2
    float* bufB    = bufA + (size_t)n * 64;    // hr1

    hipMemsetAsync(deg, 0, (size_t)n * 4, stream);
    count_kernel<<<(E + 255) / 256, 256, 0, stream>>>(dst, deg, E);
    scan_kernel<<<1, SCAN_T, 0, stream>>>(deg, row_ptr, dinv, n);
    fill_kernel<<<(E + 255) / 256, 256, 0, stream>>>(src, dst, deg, col, E);

    // Layer 1
    gemm_kernel<128, 64><<<(n + 255) / 256, 256, 0, stream>>>(x, W1, bufA, n);
    agg_relu_kernel<64><<<(n * 16 + 255) / 256, 256, 0, stream>>>(row_ptr, col, dinv,
                                                                  bufA, b1, bufB, n);
    // Layer 2 + head
    gemm_kernel<64, 32><<<(n + 255) / 256, 256, 0, stream>>>(bufB, W2, bufA, n);
    agg_final_kernel<<<(n * 8 + 255) / 256, 256, 0, stream>>>(row_ptr, col, dinv,
                                                              bufA, b2, Wc, bc, out, n);
}

// Round 7
// 289.392 us; speedup vs baseline: 3.3574x; 1.9139x over previous
//
#include <hip/hip_runtime.h>

// ---------------------------------------------------------------------------
// HabitatGNN: 2-layer GCN (self loops, symmetric norm) + linear head.
// x:[N,128] f32, edge_index:[2,E] int32, W1:[128,64], W2:[64,32], Wc:[32,1].
//
// R5: atomic scatter = 75% of runtime -> replaced with CSR + gather (R6).
// R6: single-block scan_kernel = 284us (51% of total, occupancy 0.14%).
//     -> 3-phase device-wide scan (tile_reduce / scan_bsums / tile_apply).
// ---------------------------------------------------------------------------

#define SCAN_THREADS 256
#define SCAN_PER_T   8
#define SCAN_TILE    (SCAN_THREADS * SCAN_PER_T)   // 2048 elements per block

__global__ __launch_bounds__(256) void count_kernel(const int* __restrict__ dst,
                                                    int* __restrict__ deg, int E) {
    int e = blockIdx.x * blockDim.x + threadIdx.x;
    if (e < E) atomicAdd(&deg[dst[e]], 1);
}

// Phase A: per-block tile sum.
__global__ __launch_bounds__(SCAN_THREADS) void tile_reduce_kernel(const int* __restrict__ deg,
                                                                   int* __restrict__ bsum,
                                                                   int n) {
    __shared__ int s[SCAN_THREADS];
    int t = threadIdx.x;
    int gbase = blockIdx.x * SCAN_TILE + t * SCAN_PER_T;
    int local = 0;
#pragma unroll
    for (int k = 0; k < SCAN_PER_T; ++k) {
        int i = gbase + k;
        if (i < n) local += deg[i];
    }
    s[t] = local;
    __syncthreads();
    for (int off = SCAN_THREADS / 2; off > 0; off >>= 1) {
        if (t < off) s[t] += s[t + off];
        __syncthreads();
    }
    if (t == 0) bsum[blockIdx.x] = s[0];
}

// Phase B: scan the <=256 block sums (exclusive, in place); row_ptr[n] = total.
__global__ __launch_bounds__(SCAN_THREADS) void scan_bsums_kernel(int* __restrict__ bsum,
                                                                  int* __restrict__ row_ptr,
                                                                  int nb, int n) {
    __shared__ int s[SCAN_THREADS];
    int t = threadIdx.x;
    s[t] = (t < nb) ? bsum[t] : 0;
    __syncthreads();
    for (int off = 1; off < SCAN_THREADS; off <<= 1) {
        int v = (t >= off) ? s[t - off] : 0;
        __syncthreads();
        s[t] += v;
        __syncthreads();
    }
    if (t < nb) bsum[t] = (t == 0) ? 0 : s[t - 1];   // exclusive prefix
    if (t == 0) row_ptr[n] = s[nb - 1];              // == E
}

// Phase C: re-scan tile, add block prefix; write row_ptr, cursor, dinv.
__global__ __launch_bounds__(SCAN_THREADS) void tile_apply_kernel(int* __restrict__ deg,
                                                                  const int* __restrict__ bsum,
                                                                  int* __restrict__ row_ptr,
                                                                  float* __restrict__ dinv,
                                                                  int n) {
    __shared__ int s[SCAN_THREADS];
    int t = threadIdx.x;
    int gbase = blockIdx.x * SCAN_TILE + t * SCAN_PER_T;

    int d[SCAN_PER_T];
    int inc[SCAN_PER_T];
    int run = 0;
#pragma unroll
    for (int k = 0; k < SCAN_PER_T; ++k) {
        int i = gbase + k;
        d[k] = (i < n) ? deg[i] : 0;
        run += d[k];
        inc[k] = run;                      // inclusive within thread
    }
    s[t] = run;
    __syncthreads();
    for (int off = 1; off < SCAN_THREADS; off <<= 1) {
        int v = (t >= off) ? s[t - off] : 0;
        __syncthreads();
        s[t] += v;
        __syncthreads();
    }
    int base = bsum[blockIdx.x] + ((t == 0) ? 0 : s[t - 1]);
#pragma unroll
    for (int k = 0; k < SCAN_PER_T; ++k) {
        int i = gbase + k;
        if (i < n) {
            int ex = base + inc[k] - d[k];          // exclusive prefix for i
            row_ptr[i] = ex;
            deg[i] = ex;                            // fill cursor
            dinv[i] = rsqrtf((float)(d[k] + 1));    // +1 = self loop
        }
    }
}

__global__ __launch_bounds__(256) void fill_kernel(const int* __restrict__ src,
                                                   const int* __restrict__ dst,
                                                   int* __restrict__ cursor,
                                                   int* __restrict__ col, int E) {
    int e = blockIdx.x * blockDim.x + threadIdx.x;
    if (e < E) {
        int pos = atomicAdd(&cursor[dst[e]], 1);
        col[pos] = src[e];
    }
}

// H[n, OUT] = X[n, IN] @ W[IN, OUT]; W staged in LDS, one node per thread.
template <int IN, int OUT>
__global__ __launch_bounds__(256) void gemm_kernel(const float* __restrict__ X,
                                                   const float* __restrict__ W,
                                                   float* __restrict__ H, int n) {
    __shared__ float Ws[IN * OUT];
    for (int i = threadIdx.x; i < IN * OUT / 4; i += blockDim.x)
        ((float4*)Ws)[i] = ((const float4*)W)[i];
    __syncthreads();

    int node = blockIdx.x * blockDim.x + threadIdx.x;
    if (node >= n) return;

    float acc[OUT];
#pragma unroll
    for (int j = 0; j < OUT; ++j) acc[j] = 0.f;

    const float* xr = X + (size_t)node * IN;
#pragma unroll 4
    for (int k = 0; k < IN; k += 4) {
        float4 xv = *(const float4*)(xr + k);
        const float* w0 = Ws + (k + 0) * OUT;
        const float* w1 = Ws + (k + 1) * OUT;
        const float* w2 = Ws + (k + 2) * OUT;
        const float* w3 = Ws + (k + 3) * OUT;
#pragma unroll
        for (int j = 0; j < OUT; j += 4) {
            float4 a = *(const float4*)(w0 + j);
            float4 b = *(const float4*)(w1 + j);
            float4 c = *(const float4*)(w2 + j);
            float4 dd = *(const float4*)(w3 + j);
            acc[j + 0] += xv.x * a.x + xv.y * b.x + xv.z * c.x + xv.w * dd.x;
            acc[j + 1] += xv.x * a.y + xv.y * b.y + xv.z * c.y + xv.w * dd.y;
            acc[j + 2] += xv.x * a.z + xv.y * b.z + xv.z * c.z + xv.w * dd.z;
            acc[j + 3] += xv.x * a.w + xv.y * b.w + xv.z * c.w + xv.w * dd.w;
        }
    }

    float* hr = H + (size_t)node * OUT;
#pragma unroll
    for (int j = 0; j < OUT; j += 4)
        *(float4*)(hr + j) = make_float4(acc[j], acc[j + 1], acc[j + 2], acc[j + 3]);
}

// Gather aggregation, F/4 threads per node, each owns a float4 column.
// OUT[i] = relu(dinv[i]*Sum dinv[s]*H[s] + dinv[i]^2*H[i] + b)
template <int F>
__global__ __launch_bounds__(256) void agg_relu_kernel(const int* __restrict__ row_ptr,
                                                       const int* __restrict__ col,
                                                       const float* __restrict__ dinv,
                                                       const float* __restrict__ H,
                                                       const float* __restrict__ b,
                                                       float* __restrict__ OUT, int n) {
    constexpr int TPE = F / 4;
    int t = blockIdx.x * blockDim.x + threadIdx.x;
    int node = t / TPE;
    int c = t % TPE;
    if (node >= n) return;
    int rs = row_ptr[node], re = row_ptr[node + 1];
    float di = dinv[node];
    float4 acc = make_float4(0.f, 0.f, 0.f, 0.f);
    for (int e = rs; e < re; ++e) {
        int s = col[e];
        float w = dinv[s];
        float4 v = *(const float4*)(H + (size_t)s * F + c * 4);
        acc.x += w * v.x; acc.y += w * v.y; acc.z += w * v.z; acc.w += w * v.w;
    }
    float4 hs = *(const float4*)(H + (size_t)node * F + c * 4);
    float4 bb = *(const float4*)(b + c * 4);
    float d2 = di * di;
    float4 r;
    r.x = di * acc.x + d2 * hs.x + bb.x;
    r.y = di * acc.y + d2 * hs.y + bb.y;
    r.z = di * acc.z + d2 * hs.z + bb.z;
    r.w = di * acc.w + d2 * hs.w + bb.w;
    r.x = r.x > 0.f ? r.x : 0.f;
    r.y = r.y > 0.f ? r.y : 0.f;
    r.z = r.z > 0.f ? r.z : 0.f;
    r.w = r.w > 0.f ? r.w : 0.f;
    *(float4*)(OUT + (size_t)node * F + c * 4) = r;
}

// Layer-2 aggregation fused with the classifier head:
// out[i] = relu(agg(H2)[i] + b2) . Wc + bc  (8 lanes per node, shfl reduce)
__global__ __launch_bounds__(256) void agg_final_kernel(const int* __restrict__ row_ptr,
                                                        const int* __restrict__ col,
                                                        const float* __restrict__ dinv,
                                                        const float* __restrict__ H,
                                                        const float* __restrict__ b2,
                                                        const float* __restrict__ Wc,
                                                        const float* __restrict__ bc,
                                                        float* __restrict__ out, int n) {
    constexpr int F = 32, TPE = 8;
    int t = blockIdx.x * blockDim.x + threadIdx.x;
    int node = t / TPE;
    int c = t % TPE;
    if (node >= n) return;
    int rs = row_ptr[node], re = row_ptr[node + 1];
    float di = dinv[node];
    float4 acc = make_float4(0.f, 0.f, 0.f, 0.f);
    for (int e = rs; e < re; ++e) {
        int s = col[e];
        float w = dinv[s];
        float4 v = *(const float4*)(H + (size_t)s * F + c * 4);
        acc.x += w * v.x; acc.y += w * v.y; acc.z += w * v.z; acc.w += w * v.w;
    }
    float4 hs = *(const float4*)(H + (size_t)node * F + c * 4);
    float4 bb = *(const float4*)(b2 + c * 4);
    float4 wc = *(const float4*)(Wc + c * 4);
    float d2 = di * di;
    float4 r;
    r.x = di * acc.x + d2 * hs.x + bb.x;
    r.y = di * acc.y + d2 * hs.y + bb.y;
    r.z = di * acc.z + d2 * hs.z + bb.z;
    r.w = di * acc.w + d2 * hs.w + bb.w;
    float dot = (r.x > 0.f ? r.x : 0.f) * wc.x + (r.y > 0.f ? r.y : 0.f) * wc.y +
                (r.z > 0.f ? r.z : 0.f) * wc.z + (r.w > 0.f ? r.w : 0.f) * wc.w;
    dot += __shfl_xor(dot, 1, 8);
    dot += __shfl_xor(dot, 2, 8);
    dot += __shfl_xor(dot, 4, 8);
    if (c == 0) out[node] = dot + bc[0];
}

extern "C" void kernel_launch(void* const* d_in, const int* in_sizes, int n_in,
                              void* d_out, int out_size, void* d_ws, size_t ws_size,
                              hipStream_t stream) {
    const float* x  = (const float*)d_in[0];
    const int*   ei = (const int*)d_in[1];  // int32 edge_index
    const float* W1 = (const float*)d_in[2];
    const float* b1 = (const float*)d_in[3];
    const float* W2 = (const float*)d_in[4];
    const float* b2 = (const float*)d_in[5];
    const float* Wc = (const float*)d_in[6];
    const float* bc = (const float*)d_in[7];
    float* out = (float*)d_out;

    const int n = in_sizes[0] / 128;   // 100000
    const int E = in_sizes[1] / 2;     // 600000

    const int* src = ei;
    const int* dst = ei + (size_t)E;

    const int nb = (n + SCAN_TILE - 1) / SCAN_TILE;   // 49 blocks (must be <=256)

    // ws layout (4B elems): dinv[n] | deg/cursor[n] | row_ptr[n+1] | col[E]
    //                       | bsum[256] | bufA[64n] | bufB[64n]    (~54.8 MB)
    float* dinv    = (float*)d_ws;
    int*   deg     = (int*)d_ws + n;
    int*   row_ptr = (int*)d_ws + 2 * (size_t)n;
    int*   col     = row_ptr + (n + 1);
    int*   bsum    = col + E;
    float* bufA    = (float*)(bsum + 256);     // h1, then h2
    float* bufB    = bufA + (size_t)n * 64;    // hr1

    hipMemsetAsync(deg, 0, (size_t)n * 4, stream);
    count_kernel<<<(E + 255) / 256, 256, 0, stream>>>(dst, deg, E);
    tile_reduce_kernel<<<nb, SCAN_THREADS, 0, stream>>>(deg, bsum, n);
    scan_bsums_kernel<<<1, SCAN_THREADS, 0, stream>>>(bsum, row_ptr, nb, n);
    tile_apply_kernel<<<nb, SCAN_THREADS, 0, stream>>>(deg, bsum, row_ptr, dinv, n);
    fill_kernel<<<(E + 255) / 256, 256, 0, stream>>>(src, dst, deg, col, E);

    // Layer 1
    gemm_kernel<128, 64><<<(n + 255) / 256, 256, 0, stream>>>(x, W1, bufA, n);
    agg_relu_kernel<64><<<(n * 16 + 255) / 256, 256, 0, stream>>>(row_ptr, col, dinv,
                                                                  bufA, b1, bufB, n);
    // Layer 2 + head
    gemm_kernel<64, 32><<<(n + 255) / 256, 256, 0, stream>>>(bufB, W2, bufA, n);
    agg_final_kernel<<<(n * 8 + 255) / 256, 256, 0, stream>>>(row_ptr, col, dinv,
                                                              bufA, b2, Wc, bc, out, n);
}

// Round 8
// 272.468 us; speedup vs baseline: 3.5660x; 1.0621x over previous
//
#include <hip/hip_runtime.h>

// ---------------------------------------------------------------------------
// HabitatGNN: 2-layer GCN (self loops, symmetric norm) + linear head.
// x:[N,128] f32, edge_index:[2,E] int32, W1:[128,64], W2:[64,32], Wc:[32,1].
//
// R5: atomic scatter = 75% of runtime -> CSR + gather.
// R6: single-block scan = 51% of total -> 3-phase device-wide scan.
// R7: gemm_kernel top (70us): occupancy 14%, VALUBusy 18%, uncoalesced row
//     loads. -> quad-per-node GEMM: 4 lanes/node, 16/8-wide output strips;
//     4x waves, quad-broadcast X loads (16 lines/wave-load instead of 64).
// ---------------------------------------------------------------------------

#define SCAN_THREADS 256
#define SCAN_PER_T   8
#define SCAN_TILE    (SCAN_THREADS * SCAN_PER_T)   // 2048 elements per block

__global__ __launch_bounds__(256) void count_kernel(const int* __restrict__ dst,
                                                    int* __restrict__ deg, int E) {
    int e = blockIdx.x * blockDim.x + threadIdx.x;
    if (e < E) atomicAdd(&deg[dst[e]], 1);
}

// Phase A: per-block tile sum.
__global__ __launch_bounds__(SCAN_THREADS) void tile_reduce_kernel(const int* __restrict__ deg,
                                                                   int* __restrict__ bsum,
                                                                   int n) {
    __shared__ int s[SCAN_THREADS];
    int t = threadIdx.x;
    int gbase = blockIdx.x * SCAN_TILE + t * SCAN_PER_T;
    int local = 0;
#pragma unroll
    for (int k = 0; k < SCAN_PER_T; ++k) {
        int i = gbase + k;
        if (i < n) local += deg[i];
    }
    s[t] = local;
    __syncthreads();
    for (int off = SCAN_THREADS / 2; off > 0; off >>= 1) {
        if (t < off) s[t] += s[t + off];
        __syncthreads();
    }
    if (t == 0) bsum[blockIdx.x] = s[0];
}

// Phase B: scan the <=256 block sums (exclusive, in place); row_ptr[n] = total.
__global__ __launch_bounds__(SCAN_THREADS) void scan_bsums_kernel(int* __restrict__ bsum,
                                                                  int* __restrict__ row_ptr,
                                                                  int nb, int n) {
    __shared__ int s[SCAN_THREADS];
    int t = threadIdx.x;
    s[t] = (t < nb) ? bsum[t] : 0;
    __syncthreads();
    for (int off = 1; off < SCAN_THREADS; off <<= 1) {
        int v = (t >= off) ? s[t - off] : 0;
        __syncthreads();
        s[t] += v;
        __syncthreads();
    }
    if (t < nb) bsum[t] = (t == 0) ? 0 : s[t - 1];   // exclusive prefix
    if (t == 0) row_ptr[n] = s[nb - 1];              // == E
}

// Phase C: re-scan tile, add block prefix; write row_ptr, cursor, dinv.
__global__ __launch_bounds__(SCAN_THREADS) void tile_apply_kernel(int* __restrict__ deg,
                                                                  const int* __restrict__ bsum,
                                                                  int* __restrict__ row_ptr,
                                                                  float* __restrict__ dinv,
                                                                  int n) {
    __shared__ int s[SCAN_THREADS];
    int t = threadIdx.x;
    int gbase = blockIdx.x * SCAN_TILE + t * SCAN_PER_T;

    int d[SCAN_PER_T];
    int inc[SCAN_PER_T];
    int run = 0;
#pragma unroll
    for (int k = 0; k < SCAN_PER_T; ++k) {
        int i = gbase + k;
        d[k] = (i < n) ? deg[i] : 0;
        run += d[k];
        inc[k] = run;                      // inclusive within thread
    }
    s[t] = run;
    __syncthreads();
    for (int off = 1; off < SCAN_THREADS; off <<= 1) {
        int v = (t >= off) ? s[t - off] : 0;
        __syncthreads();
        s[t] += v;
        __syncthreads();
    }
    int base = bsum[blockIdx.x] + ((t == 0) ? 0 : s[t - 1]);
#pragma unroll
    for (int k = 0; k < SCAN_PER_T; ++k) {
        int i = gbase + k;
        if (i < n) {
            int ex = base + inc[k] - d[k];          // exclusive prefix for i
            row_ptr[i] = ex;
            deg[i] = ex;                            // fill cursor
            dinv[i] = rsqrtf((float)(d[k] + 1));    // +1 = self loop
        }
    }
}

__global__ __launch_bounds__(256) void fill_kernel(const int* __restrict__ src,
                                                   const int* __restrict__ dst,
                                                   int* __restrict__ cursor,
                                                   int* __restrict__ col, int E) {
    int e = blockIdx.x * blockDim.x + threadIdx.x;
    if (e < E) {
        int pos = atomicAdd(&cursor[dst[e]], 1);
        col[pos] = src[e];
    }
}

// H[n, OUT] = X[n, IN] @ W[IN, OUT]. Quad-per-node: 4 adjacent lanes share a
// node (broadcast X loads), each owns an OUT/4-wide output strip. W in LDS.
template <int IN, int OUT>
__global__ __launch_bounds__(256) void gemm_kernel(const float* __restrict__ X,
                                                   const float* __restrict__ W,
                                                   float* __restrict__ H, int n) {
    constexpr int STRIP = OUT / 4;         // 16 (layer1) / 8 (layer2)
    __shared__ float Ws[IN * OUT];
    for (int i = threadIdx.x; i < IN * OUT / 4; i += blockDim.x)
        ((float4*)Ws)[i] = ((const float4*)W)[i];
    __syncthreads();

    int t = blockIdx.x * blockDim.x + threadIdx.x;
    int node = t >> 2;
    int strip = (t & 3) * STRIP;
    if (node >= n) return;

    float acc[STRIP];
#pragma unroll
    for (int j = 0; j < STRIP; ++j) acc[j] = 0.f;

    const float* xr = X + (size_t)node * IN;
#pragma unroll 4
    for (int k = 0; k < IN; k += 4) {
        float4 xv = *(const float4*)(xr + k);   // same addr across the quad
        const float* w0 = Ws + (k + 0) * OUT + strip;
        const float* w1 = Ws + (k + 1) * OUT + strip;
        const float* w2 = Ws + (k + 2) * OUT + strip;
        const float* w3 = Ws + (k + 3) * OUT + strip;
#pragma unroll
        for (int j = 0; j < STRIP; j += 4) {
            float4 a = *(const float4*)(w0 + j);
            float4 b = *(const float4*)(w1 + j);
            float4 c = *(const float4*)(w2 + j);
            float4 dd = *(const float4*)(w3 + j);
            acc[j + 0] += xv.x * a.x + xv.y * b.x + xv.z * c.x + xv.w * dd.x;
            acc[j + 1] += xv.x * a.y + xv.y * b.y + xv.z * c.y + xv.w * dd.y;
            acc[j + 2] += xv.x * a.z + xv.y * b.z + xv.z * c.z + xv.w * dd.z;
            acc[j + 3] += xv.x * a.w + xv.y * b.w + xv.z * c.w + xv.w * dd.w;
        }
    }

    float* hr = H + (size_t)node * OUT + strip;
#pragma unroll
    for (int j = 0; j < STRIP; j += 4)
        *(float4*)(hr + j) = make_float4(acc[j], acc[j + 1], acc[j + 2], acc[j + 3]);
}

// Gather aggregation, F/4 threads per node, each owns a float4 column.
// OUT[i] = relu(dinv[i]*Sum dinv[s]*H[s] + dinv[i]^2*H[i] + b)
template <int F>
__global__ __launch_bounds__(256) void agg_relu_kernel(const int* __restrict__ row_ptr,
                                                       const int* __restrict__ col,
                                                       const float* __restrict__ dinv,
                                                       const float* __restrict__ H,
                                                       const float* __restrict__ b,
                                                       float* __restrict__ OUT, int n) {
    constexpr int TPE = F / 4;
    int t = blockIdx.x * blockDim.x + threadIdx.x;
    int node = t / TPE;
    int c = t % TPE;
    if (node >= n) return;
    int rs = row_ptr[node], re = row_ptr[node + 1];
    float di = dinv[node];
    float4 acc = make_float4(0.f, 0.f, 0.f, 0.f);
    for (int e = rs; e < re; ++e) {
        int s = col[e];
        float w = dinv[s];
        float4 v = *(const float4*)(H + (size_t)s * F + c * 4);
        acc.x += w * v.x; acc.y += w * v.y; acc.z += w * v.z; acc.w += w * v.w;
    }
    float4 hs = *(const float4*)(H + (size_t)node * F + c * 4);
    float4 bb = *(const float4*)(b + c * 4);
    float d2 = di * di;
    float4 r;
    r.x = di * acc.x + d2 * hs.x + bb.x;
    r.y = di * acc.y + d2 * hs.y + bb.y;
    r.z = di * acc.z + d2 * hs.z + bb.z;
    r.w = di * acc.w + d2 * hs.w + bb.w;
    r.x = r.x > 0.f ? r.x : 0.f;
    r.y = r.y > 0.f ? r.y : 0.f;
    r.z = r.z > 0.f ? r.z : 0.f;
    r.w = r.w > 0.f ? r.w : 0.f;
    *(float4*)(OUT + (size_t)node * F + c * 4) = r;
}

// Layer-2 aggregation fused with the classifier head:
// out[i] = relu(agg(H2)[i] + b2) . Wc + bc  (8 lanes per node, shfl reduce)
__global__ __launch_bounds__(256) void agg_final_kernel(const int* __restrict__ row_ptr,
                                                        const int* __restrict__ col,
                                                        const float* __restrict__ dinv,
                                                        const float* __restrict__ H,
                                                        const float* __restrict__ b2,
                                                        const float* __restrict__ Wc,
                                                        const float* __restrict__ bc,
                                                        float* __restrict__ out, int n) {
    constexpr int F = 32, TPE = 8;
    int t = blockIdx.x * blockDim.x + threadIdx.x;
    int node = t / TPE;
    int c = t % TPE;
    if (node >= n) return;
    int rs = row_ptr[node], re = row_ptr[node + 1];
    float di = dinv[node];
    float4 acc = make_float4(0.f, 0.f, 0.f, 0.f);
    for (int e = rs; e < re; ++e) {
        int s = col[e];
        float w = dinv[s];
        float4 v = *(const float4*)(H + (size_t)s * F + c * 4);
        acc.x += w * v.x; acc.y += w * v.y; acc.z += w * v.z; acc.w += w * v.w;
    }
    float4 hs = *(const float4*)(H + (size_t)node * F + c * 4);
    float4 bb = *(const float4*)(b2 + c * 4);
    float4 wc = *(const float4*)(Wc + c * 4);
    float d2 = di * di;
    float4 r;
    r.x = di * acc.x + d2 * hs.x + bb.x;
    r.y = di * acc.y + d2 * hs.y + bb.y;
    r.z = di * acc.z + d2 * hs.z + bb.z;
    r.w = di * acc.w + d2 * hs.w + bb.w;
    float dot = (r.x > 0.f ? r.x : 0.f) * wc.x + (r.y > 0.f ? r.y : 0.f) * wc.y +
                (r.z > 0.f ? r.z : 0.f) * wc.z + (r.w > 0.f ? r.w : 0.f) * wc.w;
    dot += __shfl_xor(dot, 1, 8);
    dot += __shfl_xor(dot, 2, 8);
    dot += __shfl_xor(dot, 4, 8);
    if (c == 0) out[node] = dot + bc[0];
}

extern "C" void kernel_launch(void* const* d_in, const int* in_sizes, int n_in,
                              void* d_out, int out_size, void* d_ws, size_t ws_size,
                              hipStream_t stream) {
    const float* x  = (const float*)d_in[0];
    const int*   ei = (const int*)d_in[1];  // int32 edge_index
    const float* W1 = (const float*)d_in[2];
    const float* b1 = (const float*)d_in[3];
    const float* W2 = (const float*)d_in[4];
    const float* b2 = (const float*)d_in[5];
    const float* Wc = (const float*)d_in[6];
    const float* bc = (const float*)d_in[7];
    float* out = (float*)d_out;

    const int n = in_sizes[0] / 128;   // 100000
    const int E = in_sizes[1] / 2;     // 600000

    const int* src = ei;
    const int* dst = ei + (size_t)E;

    const int nb = (n + SCAN_TILE - 1) / SCAN_TILE;   // 49 blocks (must be <=256)

    // ws layout (4B elems): dinv[n] | deg/cursor[n] | row_ptr[n+1] | col[E]
    //                       | bsum[256] | bufA[64n] | bufB[64n]    (~54.8 MB)
    float* dinv    = (float*)d_ws;
    int*   deg     = (int*)d_ws + n;
    int*   row_ptr = (int*)d_ws + 2 * (size_t)n;
    int*   col     = row_ptr + (n + 1);
    int*   bsum    = col + E;
    float* bufA    = (float*)(bsum + 256);     // h1, then h2
    float* bufB    = bufA + (size_t)n * 64;    // hr1

    hipMemsetAsync(deg, 0, (size_t)n * 4, stream);
    count_kernel<<<(E + 255) / 256, 256, 0, stream>>>(dst, deg, E);
    tile_reduce_kernel<<<nb, SCAN_THREADS, 0, stream>>>(deg, bsum, n);
    scan_bsums_kernel<<<1, SCAN_THREADS, 0, stream>>>(bsum, row_ptr, nb, n);
    tile_apply_kernel<<<nb, SCAN_THREADS, 0, stream>>>(deg, bsum, row_ptr, dinv, n);
    fill_kernel<<<(E + 255) / 256, 256, 0, stream>>>(src, dst, deg, col, E);

    // Layer 1
    gemm_kernel<128, 64><<<(n * 4 + 255) / 256, 256, 0, stream>>>(x, W1, bufA, n);
    agg_relu_kernel<64><<<(n * 16 + 255) / 256, 256, 0, stream>>>(row_ptr, col, dinv,
                                                                  bufA, b1, bufB, n);
    // Layer 2 + head
    gemm_kernel<64, 32><<<(n * 4 + 255) / 256, 256, 0, stream>>>(bufB, W2, bufA, n);
    agg_final_kernel<<<(n * 8 + 255) / 256, 256, 0, stream>>>(row_ptr, col, dinv,
                                                              bufA, b2, Wc, bc, out, n);
}

// Round 9
// 271.941 us; speedup vs baseline: 3.5729x; 1.0019x over previous
//
#include <hip/hip_runtime.h>

// ---------------------------------------------------------------------------
// HabitatGNN: 2-layer GCN (self loops, symmetric norm) + linear head.
// x:[N,128] f32, edge_index:[2,E] int32, W1:[128,64], W2:[64,32], Wc:[32,1].
//
// R5: atomic scatter = 75% of runtime -> CSR + gather.
// R6: single-block scan = 51% of total -> 3-phase device-wide scan.
// R7: gemm 70us, occupancy 14% -> quad-per-node (4 lanes/node). 70->44us.
// R8: gemm still latency-bound (occ 27%, VALU 30%): 256->512 block raises
//     LDS-capped occupancy 20->32 waves/CU. agg kernels: 2-way edge unroll
//     doubles outstanding gather loads (L2/L3 latency hiding).
// ---------------------------------------------------------------------------

#define SCAN_THREADS 256
#define SCAN_PER_T   8
#define SCAN_TILE    (SCAN_THREADS * SCAN_PER_T)   // 2048 elements per block

__global__ __launch_bounds__(256) void count_kernel(const int* __restrict__ dst,
                                                    int* __restrict__ deg, int E) {
    int e = blockIdx.x * blockDim.x + threadIdx.x;
    if (e < E) atomicAdd(&deg[dst[e]], 1);
}

// Phase A: per-block tile sum.
__global__ __launch_bounds__(SCAN_THREADS) void tile_reduce_kernel(const int* __restrict__ deg,
                                                                   int* __restrict__ bsum,
                                                                   int n) {
    __shared__ int s[SCAN_THREADS];
    int t = threadIdx.x;
    int gbase = blockIdx.x * SCAN_TILE + t * SCAN_PER_T;
    int local = 0;
#pragma unroll
    for (int k = 0; k < SCAN_PER_T; ++k) {
        int i = gbase + k;
        if (i < n) local += deg[i];
    }
    s[t] = local;
    __syncthreads();
    for (int off = SCAN_THREADS / 2; off > 0; off >>= 1) {
        if (t < off) s[t] += s[t + off];
        __syncthreads();
    }
    if (t == 0) bsum[blockIdx.x] = s[0];
}

// Phase B: scan the <=256 block sums (exclusive, in place); row_ptr[n] = total.
__global__ __launch_bounds__(SCAN_THREADS) void scan_bsums_kernel(int* __restrict__ bsum,
                                                                  int* __restrict__ row_ptr,
                                                                  int nb, int n) {
    __shared__ int s[SCAN_THREADS];
    int t = threadIdx.x;
    s[t] = (t < nb) ? bsum[t] : 0;
    __syncthreads();
    for (int off = 1; off < SCAN_THREADS; off <<= 1) {
        int v = (t >= off) ? s[t - off] : 0;
        __syncthreads();
        s[t] += v;
        __syncthreads();
    }
    if (t < nb) bsum[t] = (t == 0) ? 0 : s[t - 1];   // exclusive prefix
    if (t == 0) row_ptr[n] = s[nb - 1];              // == E
}

// Phase C: re-scan tile, add block prefix; write row_ptr, cursor, dinv.
__global__ __launch_bounds__(SCAN_THREADS) void tile_apply_kernel(int* __restrict__ deg,
                                                                  const int* __restrict__ bsum,
                                                                  int* __restrict__ row_ptr,
                                                                  float* __restrict__ dinv,
                                                                  int n) {
    __shared__ int s[SCAN_THREADS];
    int t = threadIdx.x;
    int gbase = blockIdx.x * SCAN_TILE + t * SCAN_PER_T;

    int d[SCAN_PER_T];
    int inc[SCAN_PER_T];
    int run = 0;
#pragma unroll
    for (int k = 0; k < SCAN_PER_T; ++k) {
        int i = gbase + k;
        d[k] = (i < n) ? deg[i] : 0;
        run += d[k];
        inc[k] = run;                      // inclusive within thread
    }
    s[t] = run;
    __syncthreads();
    for (int off = 1; off < SCAN_THREADS; off <<= 1) {
        int v = (t >= off) ? s[t - off] : 0;
        __syncthreads();
        s[t] += v;
        __syncthreads();
    }
    int base = bsum[blockIdx.x] + ((t == 0) ? 0 : s[t - 1]);
#pragma unroll
    for (int k = 0; k < SCAN_PER_T; ++k) {
        int i = gbase + k;
        if (i < n) {
            int ex = base + inc[k] - d[k];          // exclusive prefix for i
            row_ptr[i] = ex;
            deg[i] = ex;                            // fill cursor
            dinv[i] = rsqrtf((float)(d[k] + 1));    // +1 = self loop
        }
    }
}

__global__ __launch_bounds__(256) void fill_kernel(const int* __restrict__ src,
                                                   const int* __restrict__ dst,
                                                   int* __restrict__ cursor,
                                                   int* __restrict__ col, int E) {
    int e = blockIdx.x * blockDim.x + threadIdx.x;
    if (e < E) {
        int pos = atomicAdd(&cursor[dst[e]], 1);
        col[pos] = src[e];
    }
}

// H[n, OUT] = X[n, IN] @ W[IN, OUT]. Quad-per-node: 4 adjacent lanes share a
// node (broadcast X loads), each owns an OUT/4-wide output strip. W in LDS.
// 512-thread blocks: 4 blocks x 8 waves = 32 waves/CU (LDS 32KB/block).
template <int IN, int OUT>
__global__ __launch_bounds__(512) void gemm_kernel(const float* __restrict__ X,
                                                   const float* __restrict__ W,
                                                   float* __restrict__ H, int n) {
    constexpr int STRIP = OUT / 4;         // 16 (layer1) / 8 (layer2)
    __shared__ float Ws[IN * OUT];
    for (int i = threadIdx.x; i < IN * OUT / 4; i += blockDim.x)
        ((float4*)Ws)[i] = ((const float4*)W)[i];
    __syncthreads();

    int t = blockIdx.x * blockDim.x + threadIdx.x;
    int node = t >> 2;
    int strip = (t & 3) * STRIP;
    if (node >= n) return;

    float acc[STRIP];
#pragma unroll
    for (int j = 0; j < STRIP; ++j) acc[j] = 0.f;

    const float* xr = X + (size_t)node * IN;
#pragma unroll 4
    for (int k = 0; k < IN; k += 4) {
        float4 xv = *(const float4*)(xr + k);   // same addr across the quad
        const float* w0 = Ws + (k + 0) * OUT + strip;
        const float* w1 = Ws + (k + 1) * OUT + strip;
        const float* w2 = Ws + (k + 2) * OUT + strip;
        const float* w3 = Ws + (k + 3) * OUT + strip;
#pragma unroll
        for (int j = 0; j < STRIP; j += 4) {
            float4 a = *(const float4*)(w0 + j);
            float4 b = *(const float4*)(w1 + j);
            float4 c = *(const float4*)(w2 + j);
            float4 dd = *(const float4*)(w3 + j);
            acc[j + 0] += xv.x * a.x + xv.y * b.x + xv.z * c.x + xv.w * dd.x;
            acc[j + 1] += xv.x * a.y + xv.y * b.y + xv.z * c.y + xv.w * dd.y;
            acc[j + 2] += xv.x * a.z + xv.y * b.z + xv.z * c.z + xv.w * dd.z;
            acc[j + 3] += xv.x * a.w + xv.y * b.w + xv.z * c.w + xv.w * dd.w;
        }
    }

    float* hr = H + (size_t)node * OUT + strip;
#pragma unroll
    for (int j = 0; j < STRIP; j += 4)
        *(float4*)(hr + j) = make_float4(acc[j], acc[j + 1], acc[j + 2], acc[j + 3]);
}

// Gather aggregation, F/4 threads per node, each owns a float4 column.
// OUT[i] = relu(dinv[i]*Sum dinv[s]*H[s] + dinv[i]^2*H[i] + b)
// 2-way edge unroll: doubles outstanding gather loads.
template <int F>
__global__ __launch_bounds__(256) void agg_relu_kernel(const int* __restrict__ row_ptr,
                                                       const int* __restrict__ col,
                                                       const float* __restrict__ dinv,
                                                       const float* __restrict__ H,
                                                       const float* __restrict__ b,
                                                       float* __restrict__ OUT, int n) {
    constexpr int TPE = F / 4;
    int t = blockIdx.x * blockDim.x + threadIdx.x;
    int node = t / TPE;
    int c = t % TPE;
    if (node >= n) return;
    int rs = row_ptr[node], re = row_ptr[node + 1];
    float di = dinv[node];
    float4 acc = make_float4(0.f, 0.f, 0.f, 0.f);
    int e = rs;
    for (; e + 1 < re; e += 2) {
        int s0 = col[e], s1 = col[e + 1];
        float w0 = dinv[s0], w1 = dinv[s1];
        float4 v0 = *(const float4*)(H + (size_t)s0 * F + c * 4);
        float4 v1 = *(const float4*)(H + (size_t)s1 * F + c * 4);
        acc.x += w0 * v0.x + w1 * v1.x;
        acc.y += w0 * v0.y + w1 * v1.y;
        acc.z += w0 * v0.z + w1 * v1.z;
        acc.w += w0 * v0.w + w1 * v1.w;
    }
    if (e < re) {
        int s0 = col[e];
        float w0 = dinv[s0];
        float4 v0 = *(const float4*)(H + (size_t)s0 * F + c * 4);
        acc.x += w0 * v0.x; acc.y += w0 * v0.y;
        acc.z += w0 * v0.z; acc.w += w0 * v0.w;
    }
    float4 hs = *(const float4*)(H + (size_t)node * F + c * 4);
    float4 bb = *(const float4*)(b + c * 4);
    float d2 = di * di;
    float4 r;
    r.x = di * acc.x + d2 * hs.x + bb.x;
    r.y = di * acc.y + d2 * hs.y + bb.y;
    r.z = di * acc.z + d2 * hs.z + bb.z;
    r.w = di * acc.w + d2 * hs.w + bb.w;
    r.x = r.x > 0.f ? r.x : 0.f;
    r.y = r.y > 0.f ? r.y : 0.f;
    r.z = r.z > 0.f ? r.z : 0.f;
    r.w = r.w > 0.f ? r.w : 0.f;
    *(float4*)(OUT + (size_t)node * F + c * 4) = r;
}

// Layer-2 aggregation fused with the classifier head:
// out[i] = relu(agg(H2)[i] + b2) . Wc + bc  (8 lanes per node, shfl reduce)
__global__ __launch_bounds__(256) void agg_final_kernel(const int* __restrict__ row_ptr,
                                                        const int* __restrict__ col,
                                                        const float* __restrict__ dinv,
                                                        const float* __restrict__ H,
                                                        const float* __restrict__ b2,
                                                        const float* __restrict__ Wc,
                                                        const float* __restrict__ bc,
                                                        float* __restrict__ out, int n) {
    constexpr int F = 32, TPE = 8;
    int t = blockIdx.x * blockDim.x + threadIdx.x;
    int node = t / TPE;
    int c = t % TPE;
    if (node >= n) return;
    int rs = row_ptr[node], re = row_ptr[node + 1];
    float di = dinv[node];
    float4 acc = make_float4(0.f, 0.f, 0.f, 0.f);
    int e = rs;
    for (; e + 1 < re; e += 2) {
        int s0 = col[e], s1 = col[e + 1];
        float w0 = dinv[s0], w1 = dinv[s1];
        float4 v0 = *(const float4*)(H + (size_t)s0 * F + c * 4);
        float4 v1 = *(const float4*)(H + (size_t)s1 * F + c * 4);
        acc.x += w0 * v0.x + w1 * v1.x;
        acc.y += w0 * v0.y + w1 * v1.y;
        acc.z += w0 * v0.z + w1 * v1.z;
        acc.w += w0 * v0.w + w1 * v1.w;
    }
    if (e < re) {
        int s0 = col[e];
        float w0 = dinv[s0];
        float4 v0 = *(const float4*)(H + (size_t)s0 * F + c * 4);
        acc.x += w0 * v0.x; acc.y += w0 * v0.y;
        acc.z += w0 * v0.z; acc.w += w0 * v0.w;
    }
    float4 hs = *(const float4*)(H + (size_t)node * F + c * 4);
    float4 bb = *(const float4*)(b2 + c * 4);
    float4 wc = *(const float4*)(Wc + c * 4);
    float d2 = di * di;
    float4 r;
    r.x = di * acc.x + d2 * hs.x + bb.x;
    r.y = di * acc.y + d2 * hs.y + bb.y;
    r.z = di * acc.z + d2 * hs.z + bb.z;
    r.w = di * acc.w + d2 * hs.w + bb.w;
    float dot = (r.x > 0.f ? r.x : 0.f) * wc.x + (r.y > 0.f ? r.y : 0.f) * wc.y +
                (r.z > 0.f ? r.z : 0.f) * wc.z + (r.w > 0.f ? r.w : 0.f) * wc.w;
    dot += __shfl_xor(dot, 1, 8);
    dot += __shfl_xor(dot, 2, 8);
    dot += __shfl_xor(dot, 4, 8);
    if (c == 0) out[node] = dot + bc[0];
}

extern "C" void kernel_launch(void* const* d_in, const int* in_sizes, int n_in,
                              void* d_out, int out_size, void* d_ws, size_t ws_size,
                              hipStream_t stream) {
    const float* x  = (const float*)d_in[0];
    const int*   ei = (const int*)d_in[1];  // int32 edge_index
    const float* W1 = (const float*)d_in[2];
    const float* b1 = (const float*)d_in[3];
    const float* W2 = (const float*)d_in[4];
    const float* b2 = (const float*)d_in[5];
    const float* Wc = (const float*)d_in[6];
    const float* bc = (const float*)d_in[7];
    float* out = (float*)d_out;

    const int n = in_sizes[0] / 128;   // 100000
    const int E = in_sizes[1] / 2;     // 600000

    const int* src = ei;
    const int* dst = ei + (size_t)E;

    const int nb = (n + SCAN_TILE - 1) / SCAN_TILE;   // 49 blocks (must be <=256)

    // ws layout (4B elems): dinv[n] | deg/cursor[n] | row_ptr[n+1] | col[E]
    //                       | bsum[256] | bufA[64n] | bufB[64n]    (~54.8 MB)
    float* dinv    = (float*)d_ws;
    int*   deg     = (int*)d_ws + n;
    int*   row_ptr = (int*)d_ws + 2 * (size_t)n;
    int*   col     = row_ptr + (n + 1);
    int*   bsum    = col + E;
    float* bufA    = (float*)(bsum + 256);     // h1, then h2
    float* bufB    = bufA + (size_t)n * 64;    // hr1

    hipMemsetAsync(deg, 0, (size_t)n * 4, stream);
    count_kernel<<<(E + 255) / 256, 256, 0, stream>>>(dst, deg, E);
    tile_reduce_kernel<<<nb, SCAN_THREADS, 0, stream>>>(deg, bsum, n);
    scan_bsums_kernel<<<1, SCAN_THREADS, 0, stream>>>(bsum, row_ptr, nb, n);
    tile_apply_kernel<<<nb, SCAN_THREADS, 0, stream>>>(deg, bsum, row_ptr, dinv, n);
    fill_kernel<<<(E + 255) / 256, 256, 0, stream>>>(src, dst, deg, col, E);

    // Layer 1
    gemm_kernel<128, 64><<<(n * 4 + 511) / 512, 512, 0, stream>>>(x, W1, bufA, n);
    agg_relu_kernel<64><<<(n * 16 + 255) / 256, 256, 0, stream>>>(row_ptr, col, dinv,
                                                                  bufA, b1, bufB, n);
    // Layer 2 + head
    gemm_kernel<64, 32><<<(n * 4 + 511) / 512, 512, 0, stream>>>(bufB, W2, bufA, n);
    agg_final_kernel<<<(n * 8 + 255) / 256, 256, 0, stream>>>(row_ptr, col, dinv,
                                                              bufA, b2, Wc, bc, out, n);
}